// Round 1
// baseline (204.450 us; speedup 1.0000x reference)
//
#include <hip/hip_runtime.h>

#define BS 64
#define NN 2048
#define DD 512
#define ROWS 16

// ---------- Kernel 1: content scores ----------
// score[b,n] = beta[b] * dot(M[b,n,:], k[b,:]) / (||M[b,n,:]|| * ||k[b,:]||)
// One 64-lane wave per row; 4 waves (4 rows) per 256-thread block.
__global__ __launch_bounds__(256) void k_score(const float* __restrict__ M,
                                               const float* __restrict__ k,
                                               const float* __restrict__ beta,
                                               float* __restrict__ score) {
    int wave = threadIdx.x >> 6;
    int lane = threadIdx.x & 63;
    int row  = blockIdx.x * 4 + wave;           // [0, BS*NN)
    int b    = row >> 11;                        // row / NN
    const float4* Mr = (const float4*)(M + (size_t)row * DD);
    const float4* kr = (const float4*)(k + (size_t)b * DD);
    float dot = 0.f, ssm = 0.f, ssk = 0.f;
#pragma unroll
    for (int i = 0; i < 2; ++i) {
        int idx = lane + i * 64;                 // 0..127 float4s
        float4 m4 = Mr[idx];
        float4 k4 = kr[idx];
        dot += m4.x * k4.x + m4.y * k4.y + m4.z * k4.z + m4.w * k4.w;
        ssm += m4.x * m4.x + m4.y * m4.y + m4.z * m4.z + m4.w * m4.w;
        ssk += k4.x * k4.x + k4.y * k4.y + k4.z * k4.z + k4.w * k4.w;
    }
#pragma unroll
    for (int off = 32; off > 0; off >>= 1) {
        dot += __shfl_xor(dot, off);
        ssm += __shfl_xor(ssm, off);
        ssk += __shfl_xor(ssk, off);
    }
    if (lane == 0) {
        score[row] = beta[b] * dot * rsqrtf(ssm * ssk);
    }
}

// ---------- Kernel 2: softmax + gate + circular conv + sharpen ----------
// One 256-thread block per batch; 8 elements per thread.
__device__ __forceinline__ float block_max(float v) {
    __shared__ float sm[4];
    int lane = threadIdx.x & 63, wid = threadIdx.x >> 6;
#pragma unroll
    for (int off = 32; off > 0; off >>= 1) v = fmaxf(v, __shfl_xor(v, off));
    if (lane == 0) sm[wid] = v;
    __syncthreads();
    v = fmaxf(fmaxf(sm[0], sm[1]), fmaxf(sm[2], sm[3]));
    __syncthreads();
    return v;
}
__device__ __forceinline__ float block_sum(float v) {
    __shared__ float sm[4];
    int lane = threadIdx.x & 63, wid = threadIdx.x >> 6;
#pragma unroll
    for (int off = 32; off > 0; off >>= 1) v += __shfl_xor(v, off);
    if (lane == 0) sm[wid] = v;
    __syncthreads();
    v = sm[0] + sm[1] + sm[2] + sm[3];
    __syncthreads();
    return v;
}

__global__ __launch_bounds__(256) void k_weights(const float* __restrict__ score,
                                                 const float* __restrict__ gp,
                                                 const float* __restrict__ sp,
                                                 const float* __restrict__ yp,
                                                 const float* __restrict__ w_prev,
                                                 float* __restrict__ r_out,
                                                 float* __restrict__ w_out) {
    __shared__ float v[NN];
    int b = blockIdx.x, t = threadIdx.x;
    float g  = gp[b], y = yp[b];
    float s0 = sp[b * 3 + 0], s1 = sp[b * 3 + 1], s2 = sp[b * 3 + 2];

    float loc[8];
    float mx = -1e30f;
#pragma unroll
    for (int i = 0; i < 8; ++i) {
        loc[i] = score[b * NN + t * 8 + i];
        mx = fmaxf(mx, loc[i]);
    }
    mx = block_max(mx);
    float sum = 0.f;
#pragma unroll
    for (int i = 0; i < 8; ++i) {
        loc[i] = __expf(loc[i] - mx);
        sum += loc[i];
    }
    sum = block_sum(sum);
    float inv = 1.f / sum;
#pragma unroll
    for (int i = 0; i < 8; ++i) {
        int n = t * 8 + i;
        v[n] = g * loc[i] * inv + (1.f - g) * w_prev[b * NN + n];
    }
    __syncthreads();
    float u[8];
    float psum = 0.f;
#pragma unroll
    for (int i = 0; i < 8; ++i) {
        int n  = t * 8 + i;
        int nm = (n == 0) ? NN - 1 : n - 1;
        int np = (n == NN - 1) ? 0 : n + 1;
        float uu = s2 * v[nm] + s1 * v[n] + s0 * v[np];
        uu = powf(uu, y);
        u[i] = uu;
        psum += uu;
    }
    psum = block_sum(psum);
    float pin = 1.f / psum;
#pragma unroll
    for (int i = 0; i < 8; ++i) w_out[b * NN + t * 8 + i] = u[i] * pin;
    // zero r accumulation target (re-zeroed every call; harness doesn't re-poison)
    r_out[b * DD + t]       = 0.f;
    r_out[b * DD + t + 256] = 0.f;
}

// ---------- Kernel 3: read r + write M_next ----------
// Each 256-thread block handles ROWS rows of one batch.
__global__ __launch_bounds__(256) void k_readwrite(const float* __restrict__ M,
                                                   const float* __restrict__ e,
                                                   const float* __restrict__ a,
                                                   const float* __restrict__ w,
                                                   float* __restrict__ r,
                                                   float* __restrict__ Mn) {
    int blk = blockIdx.x;
    int b   = blk / (NN / ROWS);
    int n0  = (blk % (NN / ROWS)) * ROWS;
    int t   = threadIdx.x;
    int c   = t & 127;   // float4 column
    int rh  = t >> 7;    // 0 or 1 (row within pair)

    const float4* e4 = (const float4*)(e + (size_t)b * DD);
    const float4* a4 = (const float4*)(a + (size_t)b * DD);
    float4 ev = e4[c], av = a4[c];
    float4 acc = make_float4(0.f, 0.f, 0.f, 0.f);

    const float4* Mb  = (const float4*)(M  + ((size_t)b * NN + n0) * DD);
    float4*       Mnb = (float4*)      (Mn + ((size_t)b * NN + n0) * DD);
    const float*  wb  = w + (size_t)b * NN + n0;

#pragma unroll
    for (int i = 0; i < ROWS / 2; ++i) {
        int rr = i * 2 + rh;
        float wv = wb[rr];
        float4 m4 = Mb[rr * 128 + c];
        acc.x += wv * m4.x;
        acc.y += wv * m4.y;
        acc.z += wv * m4.z;
        acc.w += wv * m4.w;
        float4 o;
        o.x = m4.x * (1.f - wv * ev.x) + wv * av.x;
        o.y = m4.y * (1.f - wv * ev.y) + wv * av.y;
        o.z = m4.z * (1.f - wv * ev.z) + wv * av.z;
        o.w = m4.w * (1.f - wv * ev.w) + wv * av.w;
        Mnb[rr * 128 + c] = o;
    }

    __shared__ float4 sacc[128];
    if (rh == 1) sacc[c] = acc;
    __syncthreads();
    if (rh == 0) {
        float4 o = sacc[c];
        acc.x += o.x; acc.y += o.y; acc.z += o.z; acc.w += o.w;
        float* rb = r + (size_t)b * DD + c * 4;
        atomicAdd(rb + 0, acc.x);
        atomicAdd(rb + 1, acc.y);
        atomicAdd(rb + 2, acc.z);
        atomicAdd(rb + 3, acc.w);
    }
}

extern "C" void kernel_launch(void* const* d_in, const int* in_sizes, int n_in,
                              void* d_out, int out_size, void* d_ws, size_t ws_size,
                              hipStream_t stream) {
    const float* M      = (const float*)d_in[0];
    const float* k      = (const float*)d_in[1];
    const float* beta   = (const float*)d_in[2];
    const float* g      = (const float*)d_in[3];
    const float* s      = (const float*)d_in[4];
    const float* y      = (const float*)d_in[5];
    const float* e      = (const float*)d_in[6];
    const float* a      = (const float*)d_in[7];
    const float* w_prev = (const float*)d_in[8];

    float* out = (float*)d_out;
    float* r   = out;                       // [BS, DD]
    float* w   = out + BS * DD;             // [BS, NN]
    float* Mn  = out + BS * DD + BS * NN;   // [BS, NN, DD]

    // scratch for scores; fall back to the (later fully overwritten) M_next
    // region if ws is too small — safe under stream ordering.
    float* score = (ws_size >= (size_t)BS * NN * sizeof(float)) ? (float*)d_ws : Mn;

    k_score   <<<BS * NN / 4,      256, 0, stream>>>(M, k, beta, score);
    k_weights <<<BS,               256, 0, stream>>>(score, g, s, y, w_prev, r, w);
    k_readwrite<<<BS * (NN / ROWS), 256, 0, stream>>>(M, e, a, w, r, Mn);
}

// Round 3
// 146.971 us; speedup vs baseline: 1.3911x; 1.3911x over previous
//
#include <hip/hip_runtime.h>

#define BS 64
#define NN 2048
#define DD 512
#define ROWS 32
#define BPB (NN / ROWS)   // blocks per batch in pass 2 = 64

typedef float f32x4 __attribute__((ext_vector_type(4)));

// ---------- Kernel 1: content scores ----------
// score[b,n] = beta[b] * dot(M[b,n,:], k[b,:]) / (||M[b,n,:]|| * ||k[b,:]||)
// One 64-lane wave per row; 4 waves (4 rows) per 256-thread block.
__global__ __launch_bounds__(256) void k_score(const float* __restrict__ M,
                                               const float* __restrict__ k,
                                               const float* __restrict__ beta,
                                               float* __restrict__ score) {
    int wave = threadIdx.x >> 6;
    int lane = threadIdx.x & 63;
    int row  = blockIdx.x * 4 + wave;           // [0, BS*NN)
    int b    = row >> 11;                        // row / NN
    const float4* Mr = (const float4*)(M + (size_t)row * DD);
    const float4* kr = (const float4*)(k + (size_t)b * DD);
    float dot = 0.f, ssm = 0.f, ssk = 0.f;
#pragma unroll
    for (int i = 0; i < 2; ++i) {
        int idx = lane + i * 64;                 // 0..127 float4s
        float4 m4 = Mr[idx];
        float4 k4 = kr[idx];
        dot += m4.x * k4.x + m4.y * k4.y + m4.z * k4.z + m4.w * k4.w;
        ssm += m4.x * m4.x + m4.y * m4.y + m4.z * m4.z + m4.w * m4.w;
        ssk += k4.x * k4.x + k4.y * k4.y + k4.z * k4.z + k4.w * k4.w;
    }
#pragma unroll
    for (int off = 32; off > 0; off >>= 1) {
        dot += __shfl_xor(dot, off);
        ssm += __shfl_xor(ssm, off);
        ssk += __shfl_xor(ssk, off);
    }
    if (lane == 0) {
        score[row] = beta[b] * dot * rsqrtf(ssm * ssk);
    }
}

// ---------- Kernel 2: softmax + gate + circular conv + sharpen ----------
__device__ __forceinline__ float block_max(float v) {
    __shared__ float sm[4];
    int lane = threadIdx.x & 63, wid = threadIdx.x >> 6;
#pragma unroll
    for (int off = 32; off > 0; off >>= 1) v = fmaxf(v, __shfl_xor(v, off));
    if (lane == 0) sm[wid] = v;
    __syncthreads();
    v = fmaxf(fmaxf(sm[0], sm[1]), fmaxf(sm[2], sm[3]));
    __syncthreads();
    return v;
}
__device__ __forceinline__ float block_sum(float v) {
    __shared__ float sm[4];
    int lane = threadIdx.x & 63, wid = threadIdx.x >> 6;
#pragma unroll
    for (int off = 32; off > 0; off >>= 1) v += __shfl_xor(v, off);
    if (lane == 0) sm[wid] = v;
    __syncthreads();
    v = sm[0] + sm[1] + sm[2] + sm[3];
    __syncthreads();
    return v;
}

__global__ __launch_bounds__(256) void k_weights(const float* __restrict__ score,
                                                 const float* __restrict__ gp,
                                                 const float* __restrict__ sp,
                                                 const float* __restrict__ yp,
                                                 const float* __restrict__ w_prev,
                                                 float* __restrict__ w_out) {
    __shared__ float v[NN];
    int b = blockIdx.x, t = threadIdx.x;
    float g  = gp[b], y = yp[b];
    float s0 = sp[b * 3 + 0], s1 = sp[b * 3 + 1], s2 = sp[b * 3 + 2];

    float loc[8];
    float mx = -1e30f;
#pragma unroll
    for (int i = 0; i < 8; ++i) {
        loc[i] = score[b * NN + t * 8 + i];
        mx = fmaxf(mx, loc[i]);
    }
    mx = block_max(mx);
    float sum = 0.f;
#pragma unroll
    for (int i = 0; i < 8; ++i) {
        loc[i] = __expf(loc[i] - mx);
        sum += loc[i];
    }
    sum = block_sum(sum);
    float inv = 1.f / sum;
#pragma unroll
    for (int i = 0; i < 8; ++i) {
        int n = t * 8 + i;
        v[n] = g * loc[i] * inv + (1.f - g) * w_prev[b * NN + n];
    }
    __syncthreads();
    float u[8];
    float psum = 0.f;
#pragma unroll
    for (int i = 0; i < 8; ++i) {
        int n  = t * 8 + i;
        int nm = (n == 0) ? NN - 1 : n - 1;
        int np = (n == NN - 1) ? 0 : n + 1;
        float uu = s2 * v[nm] + s1 * v[n] + s0 * v[np];
        uu = powf(uu, y);
        u[i] = uu;
        psum += uu;
    }
    psum = block_sum(psum);
    float pin = 1.f / psum;
#pragma unroll
    for (int i = 0; i < 8; ++i) w_out[b * NN + t * 8 + i] = u[i] * pin;
}

// ---------- Kernel 3: write M_next + per-block partial r ----------
// Each 256-thread block handles ROWS rows of one batch; 4-wide load batching
// for MLP; NO atomics — partial r goes to ws, reduced by k_reduce.
__global__ __launch_bounds__(256) void k_readwrite(const float* __restrict__ M,
                                                   const float* __restrict__ e,
                                                   const float* __restrict__ a,
                                                   const float* __restrict__ w,
                                                   float* __restrict__ part,
                                                   float* __restrict__ Mn) {
    int blk = blockIdx.x;
    int b   = blk / BPB;
    int n0  = (blk % BPB) * ROWS;
    int t   = threadIdx.x;
    int c   = t & 127;   // float4 column
    int rh  = t >> 7;    // 0 or 1 (row parity)

    const float4* e4 = (const float4*)(e + (size_t)b * DD);
    const float4* a4 = (const float4*)(a + (size_t)b * DD);
    float4 ev = e4[c], av = a4[c];
    float4 acc = make_float4(0.f, 0.f, 0.f, 0.f);

    const float4* Mb  = (const float4*)(M  + ((size_t)b * NN + n0) * DD);
    f32x4*        Mnb = (f32x4*)       (Mn + ((size_t)b * NN + n0) * DD);
    const float*  wb  = w + (size_t)b * NN + n0;

#pragma unroll
    for (int i = 0; i < 4; ++i) {
        float  wv[4];
        float4 m4[4];
#pragma unroll
        for (int j = 0; j < 4; ++j) {
            int rr = (i * 4 + j) * 2 + rh;
            wv[j] = wb[rr];
            m4[j] = Mb[rr * 128 + c];
        }
#pragma unroll
        for (int j = 0; j < 4; ++j) {
            int rr = (i * 4 + j) * 2 + rh;
            acc.x += wv[j] * m4[j].x;
            acc.y += wv[j] * m4[j].y;
            acc.z += wv[j] * m4[j].z;
            acc.w += wv[j] * m4[j].w;
            f32x4 o;
            o.x = m4[j].x * (1.f - wv[j] * ev.x) + wv[j] * av.x;
            o.y = m4[j].y * (1.f - wv[j] * ev.y) + wv[j] * av.y;
            o.z = m4[j].z * (1.f - wv[j] * ev.z) + wv[j] * av.z;
            o.w = m4[j].w * (1.f - wv[j] * ev.w) + wv[j] * av.w;
            __builtin_nontemporal_store(o, &Mnb[rr * 128 + c]);
        }
    }

    __shared__ float4 sacc[128];
    if (rh == 1) sacc[c] = acc;
    __syncthreads();
    if (rh == 0) {
        float4 o = sacc[c];
        acc.x += o.x; acc.y += o.y; acc.z += o.z; acc.w += o.w;
        ((float4*)(part + (size_t)blk * DD))[c] = acc;
    }
}

// ---------- Kernel 4: reduce partial r ----------
// One 256-thread block per batch; folds BPB partials into r[b,:].
__global__ __launch_bounds__(256) void k_reduce(const float* __restrict__ part,
                                               float* __restrict__ r) {
    int b  = blockIdx.x;
    int t  = threadIdx.x;
    int c  = t & 127;
    int rh = t >> 7;
    const float4* pb = (const float4*)(part + (size_t)b * BPB * DD);
    float4 acc = make_float4(0.f, 0.f, 0.f, 0.f);
    for (int j = rh * (BPB / 2); j < (rh + 1) * (BPB / 2); ++j) {
        float4 p = pb[(size_t)j * 128 + c];
        acc.x += p.x; acc.y += p.y; acc.z += p.z; acc.w += p.w;
    }
    __shared__ float4 sacc[128];
    if (rh == 1) sacc[c] = acc;
    __syncthreads();
    if (rh == 0) {
        float4 o = sacc[c];
        acc.x += o.x; acc.y += o.y; acc.z += o.z; acc.w += o.w;
        ((float4*)(r + (size_t)b * DD))[c] = acc;
    }
}

extern "C" void kernel_launch(void* const* d_in, const int* in_sizes, int n_in,
                              void* d_out, int out_size, void* d_ws, size_t ws_size,
                              hipStream_t stream) {
    const float* M      = (const float*)d_in[0];
    const float* k      = (const float*)d_in[1];
    const float* beta   = (const float*)d_in[2];
    const float* g      = (const float*)d_in[3];
    const float* s      = (const float*)d_in[4];
    const float* y      = (const float*)d_in[5];
    const float* e      = (const float*)d_in[6];
    const float* a      = (const float*)d_in[7];
    const float* w_prev = (const float*)d_in[8];

    float* out = (float*)d_out;
    float* r   = out;                       // [BS, DD]
    float* w   = out + BS * DD;             // [BS, NN]
    float* Mn  = out + BS * DD + BS * NN;   // [BS, NN, DD]

    float* score = (float*)d_ws;                 // BS*NN floats   (512 KB)
    float* part  = score + BS * NN;              // BS*BPB*DD floats (8 MB)

    k_score    <<<BS * NN / 4, 256, 0, stream>>>(M, k, beta, score);
    k_weights  <<<BS,          256, 0, stream>>>(score, g, s, y, w_prev, w);
    k_readwrite<<<BS * BPB,    256, 0, stream>>>(M, e, a, w, part, Mn);
    k_reduce   <<<BS,          256, 0, stream>>>(part, r);
}

// Round 4
// 143.017 us; speedup vs baseline: 1.4296x; 1.0277x over previous
//
#include <hip/hip_runtime.h>

#define BS 64
#define NN 2048
#define DD 512
#define ROWS 64
#define BPB (NN / ROWS)   // blocks per batch in pass 2 = 32

typedef float f32x4 __attribute__((ext_vector_type(4)));

// ---------- Kernel 1: content scores ----------
// score[b,n] = beta[b] * dot(M[b,n,:], k[b,:]) / (||M[b,n,:]|| * ||k[b,:]||)
// One 64-lane wave per row; 4 waves (4 rows) per 256-thread block.
// Plain (caching) loads on purpose: this pass populates L3 with M for pass 2.
__global__ __launch_bounds__(256) void k_score(const float* __restrict__ M,
                                               const float* __restrict__ k,
                                               const float* __restrict__ beta,
                                               float* __restrict__ score) {
    int wave = threadIdx.x >> 6;
    int lane = threadIdx.x & 63;
    int row  = blockIdx.x * 4 + wave;           // [0, BS*NN)
    int b    = row >> 11;                        // row / NN
    const float4* Mr = (const float4*)(M + (size_t)row * DD);
    const float4* kr = (const float4*)(k + (size_t)b * DD);
    float dot = 0.f, ssm = 0.f, ssk = 0.f;
#pragma unroll
    for (int i = 0; i < 2; ++i) {
        int idx = lane + i * 64;                 // 0..127 float4s
        float4 m4 = Mr[idx];
        float4 k4 = kr[idx];
        dot += m4.x * k4.x + m4.y * k4.y + m4.z * k4.z + m4.w * k4.w;
        ssm += m4.x * m4.x + m4.y * m4.y + m4.z * m4.z + m4.w * m4.w;
        ssk += k4.x * k4.x + k4.y * k4.y + k4.z * k4.z + k4.w * k4.w;
    }
#pragma unroll
    for (int off = 32; off > 0; off >>= 1) {
        dot += __shfl_xor(dot, off);
        ssm += __shfl_xor(ssm, off);
        ssk += __shfl_xor(ssk, off);
    }
    if (lane == 0) {
        score[row] = beta[b] * dot * rsqrtf(ssm * ssk);
    }
}

// ---------- Kernel 2: softmax + gate + circular conv + sharpen ----------
__device__ __forceinline__ float block_max(float v) {
    __shared__ float sm[4];
    int lane = threadIdx.x & 63, wid = threadIdx.x >> 6;
#pragma unroll
    for (int off = 32; off > 0; off >>= 1) v = fmaxf(v, __shfl_xor(v, off));
    if (lane == 0) sm[wid] = v;
    __syncthreads();
    v = fmaxf(fmaxf(sm[0], sm[1]), fmaxf(sm[2], sm[3]));
    __syncthreads();
    return v;
}
__device__ __forceinline__ float block_sum(float v) {
    __shared__ float sm[4];
    int lane = threadIdx.x & 63, wid = threadIdx.x >> 6;
#pragma unroll
    for (int off = 32; off > 0; off >>= 1) v += __shfl_xor(v, off);
    if (lane == 0) sm[wid] = v;
    __syncthreads();
    v = sm[0] + sm[1] + sm[2] + sm[3];
    __syncthreads();
    return v;
}

__global__ __launch_bounds__(256) void k_weights(const float* __restrict__ score,
                                                 const float* __restrict__ gp,
                                                 const float* __restrict__ sp,
                                                 const float* __restrict__ yp,
                                                 const float* __restrict__ w_prev,
                                                 float* __restrict__ w_out) {
    __shared__ float v[NN];
    int b = blockIdx.x, t = threadIdx.x;
    float g  = gp[b], y = yp[b];
    float s0 = sp[b * 3 + 0], s1 = sp[b * 3 + 1], s2 = sp[b * 3 + 2];

    float loc[8];
    float mx = -1e30f;
#pragma unroll
    for (int i = 0; i < 8; ++i) {
        loc[i] = score[b * NN + t * 8 + i];
        mx = fmaxf(mx, loc[i]);
    }
    mx = block_max(mx);
    float sum = 0.f;
#pragma unroll
    for (int i = 0; i < 8; ++i) {
        loc[i] = __expf(loc[i] - mx);
        sum += loc[i];
    }
    sum = block_sum(sum);
    float inv = 1.f / sum;
#pragma unroll
    for (int i = 0; i < 8; ++i) {
        int n = t * 8 + i;
        v[n] = g * loc[i] * inv + (1.f - g) * w_prev[b * NN + n];
    }
    __syncthreads();
    float u[8];
    float psum = 0.f;
#pragma unroll
    for (int i = 0; i < 8; ++i) {
        int n  = t * 8 + i;
        int nm = (n == 0) ? NN - 1 : n - 1;
        int np = (n == NN - 1) ? 0 : n + 1;
        float uu = s2 * v[nm] + s1 * v[n] + s0 * v[np];
        uu = powf(uu, y);
        u[i] = uu;
        psum += uu;
    }
    psum = block_sum(psum);
    float pin = 1.f / psum;
#pragma unroll
    for (int i = 0; i < 8; ++i) w_out[b * NN + t * 8 + i] = u[i] * pin;
}

// ---------- Kernel 3: write M_next + per-block partial r ----------
// REVERSED block order: first rows touched are the most-recently-cached from
// k_score's forward pass (L3 LRU synergy). NT loads (last use of M, don't
// re-promote) + NT stores (pure output stream, don't pollute L3).
__global__ __launch_bounds__(256) void k_readwrite(const float* __restrict__ M,
                                                   const float* __restrict__ e,
                                                   const float* __restrict__ a,
                                                   const float* __restrict__ w,
                                                   float* __restrict__ part,
                                                   float* __restrict__ Mn) {
    int blk = (int)gridDim.x - 1 - (int)blockIdx.x;   // reverse for L3 LRU
    int b   = blk / BPB;
    int n0  = (blk % BPB) * ROWS;
    int t   = threadIdx.x;
    int c   = t & 127;   // float4 column
    int rh  = t >> 7;    // 0 or 1 (row parity)

    const f32x4* e4 = (const f32x4*)(e + (size_t)b * DD);
    const f32x4* a4 = (const f32x4*)(a + (size_t)b * DD);
    f32x4 ev = e4[c], av = a4[c];
    f32x4 acc = (f32x4)(0.f);

    const f32x4* Mb  = (const f32x4*)(M  + ((size_t)b * NN + n0) * DD);
    f32x4*       Mnb = (f32x4*)      (Mn + ((size_t)b * NN + n0) * DD);
    const float* wb  = w + (size_t)b * NN + n0;

    for (int i = 0; i < ROWS / 8; ++i) {
        float  wv[4];
        f32x4  m4[4];
#pragma unroll
        for (int j = 0; j < 4; ++j) {
            int rr = (i * 4 + j) * 2 + rh;
            wv[j] = wb[rr];
            m4[j] = __builtin_nontemporal_load(&Mb[rr * 128 + c]);
        }
#pragma unroll
        for (int j = 0; j < 4; ++j) {
            int rr = (i * 4 + j) * 2 + rh;
            acc += wv[j] * m4[j];
            f32x4 o = m4[j] * (1.f - wv[j] * ev) + wv[j] * av;
            __builtin_nontemporal_store(o, &Mnb[rr * 128 + c]);
        }
    }

    __shared__ f32x4 sacc[128];
    if (rh == 1) sacc[c] = acc;
    __syncthreads();
    if (rh == 0) {
        acc += sacc[c];
        ((f32x4*)(part + (size_t)blk * DD))[c] = acc;
    }
}

// ---------- Kernel 4: reduce partial r ----------
__global__ __launch_bounds__(256) void k_reduce(const float* __restrict__ part,
                                               float* __restrict__ r) {
    int b  = blockIdx.x;
    int t  = threadIdx.x;
    int c  = t & 127;
    int rh = t >> 7;
    const f32x4* pb = (const f32x4*)(part + (size_t)b * BPB * DD);
    f32x4 acc = (f32x4)(0.f);
    for (int j = rh * (BPB / 2); j < (rh + 1) * (BPB / 2); ++j) {
        acc += pb[(size_t)j * 128 + c];
    }
    __shared__ f32x4 sacc[128];
    if (rh == 1) sacc[c] = acc;
    __syncthreads();
    if (rh == 0) {
        acc += sacc[c];
        ((f32x4*)(r + (size_t)b * DD))[c] = acc;
    }
}

extern "C" void kernel_launch(void* const* d_in, const int* in_sizes, int n_in,
                              void* d_out, int out_size, void* d_ws, size_t ws_size,
                              hipStream_t stream) {
    const float* M      = (const float*)d_in[0];
    const float* k      = (const float*)d_in[1];
    const float* beta   = (const float*)d_in[2];
    const float* g      = (const float*)d_in[3];
    const float* s      = (const float*)d_in[4];
    const float* y      = (const float*)d_in[5];
    const float* e      = (const float*)d_in[6];
    const float* a      = (const float*)d_in[7];
    const float* w_prev = (const float*)d_in[8];

    float* out = (float*)d_out;
    float* r   = out;                       // [BS, DD]
    float* w   = out + BS * DD;             // [BS, NN]
    float* Mn  = out + BS * DD + BS * NN;   // [BS, NN, DD]

    float* score = (float*)d_ws;                 // BS*NN floats   (512 KB)
    float* part  = score + BS * NN;              // BS*BPB*DD floats (4 MB)

    k_score    <<<BS * NN / 4, 256, 0, stream>>>(M, k, beta, score);
    k_weights  <<<BS,          256, 0, stream>>>(score, g, s, y, w_prev, w);
    k_readwrite<<<BS * BPB,    256, 0, stream>>>(M, e, a, w, part, Mn);
    k_reduce   <<<BS,          256, 0, stream>>>(part, r);
}